// Round 3
// baseline (3383.472 us; speedup 1.0000x reference)
//
#include <hip/hip_runtime.h>
#include <hip/hip_bf16.h>

#define VOCAB 100
#define EMB   32
#define HID   64
#define G4    256
#define TT    200
#define BATCH 8192
#define NOUT  32
#define BT    16

// LDS h-plane geometry (units: shorts).
// HI block: [layer(2)][parity(2)][row(16)][unit(64)] = 4096 shorts, then 16-short pad,
// then LO block (same layout) at +4112 shorts => LO banks = HI banks + 8 dwords (mod 32)
// => HI-writes and LO-writes of one instruction land on complementary bank halves.
#define REGB(l, p) (((l) * 2 + (p)) * 1024)
#define LOOFF 4112
#define HSSZ  8208

typedef __attribute__((ext_vector_type(8))) short short8;
typedef __attribute__((ext_vector_type(4))) float floatx4;

__device__ __forceinline__ unsigned short f2bf(float x) {
    unsigned int b = __float_as_uint(x);
    b += 0x7FFFu + ((b >> 16) & 1u);
    return (unsigned short)(b >> 16);
}
__device__ __forceinline__ float bf2f(unsigned short u) {
    return __uint_as_float(((unsigned int)u) << 16);
}
__device__ __forceinline__ float sigf(float x) {
    return __builtin_amdgcn_rcpf(1.0f + exp2f(x * -1.4426950408889634f));
}
__device__ __forceinline__ float tanhf_(float x) {
    return 1.0f - 2.0f * __builtin_amdgcn_rcpf(1.0f + exp2f(x * 2.8853900817779268f));
}
__device__ __forceinline__ void split8(const float* __restrict__ src, short8& hi, short8& lo) {
#pragma unroll
    for (int j = 0; j < 8; ++j) {
        float w = src[j];
        unsigned short h = f2bf(w);
        unsigned short l = f2bf(w - bf2f(h));
        hi[j] = (short)h;
        lo[j] = (short)l;
    }
}

// lut[v][unit][gate] (gate-minor float4) = bih0+bhh0 + emb[v] . Wih0-row
__global__ void build_lut(const float* __restrict__ emb, const float* __restrict__ Wih0,
                          const float* __restrict__ bih0, const float* __restrict__ bhh0,
                          float* __restrict__ lut) {
    const int v = blockIdx.x;
    const int j = threadIdx.x;
    const float* e = emb + v * EMB;
    const float* w = Wih0 + j * EMB;
    float s = bih0[j] + bhh0[j];
#pragma unroll
    for (int k = 0; k < EMB; ++k) s = fmaf(e[k], w[k], s);
    lut[v * G4 + (j & 63) * 4 + (j >> 6)] = s;
}

#define MFMA(a, b, c) __builtin_amdgcn_mfma_f32_16x16x32_bf16((a), (b), (c), 0, 0, 0)

// pack pair (u_even,u_odd) hi->one dword / lo->one dword; even lane stores HI, odd stores LO.
#define PAIRPACK_STORE(hval, basep, off)                                            \
    {                                                                               \
        const float ho_ = __shfl_xor((hval), 1, 64);                                \
        const float hf_ = sel ? ho_ : (hval);                                       \
        const float hs_ = sel ? (hval) : ho_;                                       \
        unsigned int hw_;                                                           \
        asm("v_cvt_pk_bf16_f32 %0, %1, %2" : "=v"(hw_) : "v"(hf_), "v"(hs_));       \
        const float rlo_ = hf_ - __uint_as_float(hw_ << 16);                        \
        const float rhi_ = hs_ - __uint_as_float(hw_ & 0xffff0000u);                \
        unsigned int lw_;                                                           \
        asm("v_cvt_pk_bf16_f32 %0, %1, %2" : "=v"(lw_) : "v"(rlo_), "v"(rhi_));     \
        *(unsigned int*)&(basep)[(off)] = sel ? lw_ : hw_;                          \
    }

// One LSTM time step at compile-time parity P. LV = current lut float4[4], LVN = prefetch dst.
#define STEP(P, LV, LVN, tcur)                                                      \
    {                                                                               \
        const unsigned short* b0_ = &hs[REGB(0, (P))];                              \
        short8 ah0 = *(const short8*)&b0_[rdA0];                                    \
        short8 ah1 = *(const short8*)&b0_[rdA1];                                    \
        short8 al0 = *(const short8*)&b0_[rdA0 + LOOFF];                            \
        short8 al1 = *(const short8*)&b0_[rdA1 + LOOFF];                            \
        floatx4 g0[4];                                                              \
        _Pragma("unroll")                                                           \
        for (int ci = 0; ci < 4; ++ci) {                                            \
            floatx4 d = {0.f, 0.f, 0.f, 0.f};                                       \
            d = MFMA(ah0, w0h[ci][0], d); d = MFMA(ah1, w0h[ci][1], d);             \
            d = MFMA(al0, w0h[ci][0], d); d = MFMA(al1, w0h[ci][1], d);             \
            d = MFMA(ah0, w0l[ci][0], d); d = MFMA(ah1, w0l[ci][1], d);             \
            g0[ci] = d;                                                             \
        }                                                                           \
        int xa_[4];                                                                 \
        *(int4*)xa_ = *(const int4*)&xsT[((tcur) + 1) * BT + lkb * 4];              \
        _Pragma("unroll")                                                           \
        for (int m2 = 0; m2 < 4; ++m2) LVN[m2] = lut4[xa_[m2] * 64 + u];            \
        unsigned short* wb0_ = &hs[REGB(0, (P) ^ 1)];                               \
        _Pragma("unroll")                                                           \
        for (int m = 0; m < 4; ++m) {                                               \
            const float gi = g0[0][m] + LV[m].x;                                    \
            const float gf = g0[1][m] + LV[m].y;                                    \
            const float gg = g0[2][m] + LV[m].z;                                    \
            const float go = g0[3][m] + LV[m].w;                                    \
            const float c = sigf(gf) * c0[m] + sigf(gi) * tanhf_(gg);               \
            c0[m] = c;                                                              \
            const float h = sigf(go) * tanhf_(c);                                   \
            PAIRPACK_STORE(h, wb0_, wr[m]);                                         \
        }                                                                           \
        __syncthreads();                                                            \
        const unsigned short* c0_ = &hs[REGB(0, (P) ^ 1)];                          \
        const unsigned short* c1_ = &hs[REGB(1, (P))];                              \
        short8 f0 = *(const short8*)&c0_[rdA0];                                     \
        short8 f1 = *(const short8*)&c0_[rdA1];                                     \
        short8 f2 = *(const short8*)&c1_[rdA0];                                     \
        short8 f3 = *(const short8*)&c1_[rdA1];                                     \
        floatx4 g1[4];                                                              \
        _Pragma("unroll")                                                           \
        for (int ci = 0; ci < 4; ++ci) {                                            \
            floatx4 d = {b1v[ci], b1v[ci], b1v[ci], b1v[ci]};                       \
            d = MFMA(f0, w1h[ci][0], d); d = MFMA(f1, w1h[ci][1], d);               \
            d = MFMA(f2, w1h[ci][2], d); d = MFMA(f3, w1h[ci][3], d);               \
            d = MFMA(f0, w1l[ci][0], d); d = MFMA(f1, w1l[ci][1], d);               \
            d = MFMA(f2, w1l[ci][2], d); d = MFMA(f3, w1l[ci][3], d);               \
            g1[ci] = d;                                                             \
        }                                                                           \
        f0 = *(const short8*)&c0_[rdA0 + LOOFF];                                    \
        f1 = *(const short8*)&c0_[rdA1 + LOOFF];                                    \
        f2 = *(const short8*)&c1_[rdA0 + LOOFF];                                    \
        f3 = *(const short8*)&c1_[rdA1 + LOOFF];                                    \
        _Pragma("unroll")                                                           \
        for (int ci = 0; ci < 4; ++ci) {                                            \
            floatx4 d = g1[ci];                                                     \
            d = MFMA(f0, w1h[ci][0], d); d = MFMA(f1, w1h[ci][1], d);               \
            d = MFMA(f2, w1h[ci][2], d); d = MFMA(f3, w1h[ci][3], d);               \
            g1[ci] = d;                                                             \
        }                                                                           \
        unsigned short* wb1_ = &hs[REGB(1, (P) ^ 1)];                               \
        _Pragma("unroll")                                                           \
        for (int m = 0; m < 4; ++m) {                                               \
            const float c = sigf(g1[1][m]) * c1[m] + sigf(g1[0][m]) * tanhf_(g1[2][m]); \
            c1[m] = c;                                                              \
            const float h = sigf(g1[3][m]) * tanhf_(c);                             \
            PAIRPACK_STORE(h, wb1_, wr[m]);                                         \
        }                                                                           \
    }

__global__ void lstm_mfma(
    const int*   __restrict__ x,
    const float* __restrict__ Whh0,
    const float* __restrict__ Wih1,
    const float* __restrict__ Whh1,
    const float* __restrict__ bih1,
    const float* __restrict__ bhh1,
    const float* __restrict__ Wfc,
    const float* __restrict__ bfc,
    const float* __restrict__ lut,
    float* __restrict__ out) {

    __shared__ __align__(16) unsigned short hs[HSSZ];
    __shared__ __align__(16) int xsT[(TT + 1) * BT];

    const int tid  = threadIdx.x;
    const int lane = tid & 63;
    const int q    = tid >> 6;
    const int r0   = blockIdx.x * BT;

    // stage x transposed: xsT[t][r]
    for (int i = tid; i < BT * TT; i += 256) {
        const int r = i / TT, t = i - r * TT;
        xsT[t * BT + r] = x[r0 * TT + i];
    }
    if (tid < BT) xsT[TT * BT + tid] = 0;   // pad row (prefetch of t=200)
    for (int i = tid; i < HSSZ; i += 256) hs[i] = 0;

    const int mcol = lane & 15;
    const int lkb  = lane >> 4;
    const int u    = q * 16 + mcol;
    const int sel  = mcol & 1;

    // ---- preload weight B-frags (hi/lo split) ----
    short8 w0h[4][2], w0l[4][2], w1h[4][4], w1l[4][4];
    float  b1v[4];
#pragma unroll
    for (int ci = 0; ci < 4; ++ci) {
        const int jw = (q + ci * 4) * 16 + mcol;
#pragma unroll
        for (int kb = 0; kb < 2; ++kb)
            split8(Whh0 + jw * HID + kb * 32 + lkb * 8, w0h[ci][kb], w0l[ci][kb]);
#pragma unroll
        for (int kb = 0; kb < 4; ++kb) {
            const int k = kb * 32 + lkb * 8;
            const float* src = (k < 64) ? (Wih1 + jw * HID + k)
                                        : (Whh1 + jw * HID + (k - 64));
            split8(src, w1h[ci][kb], w1l[ci][kb]);
        }
        b1v[ci] = bih1[jw] + bhh1[jw];
    }

    // ---- hoisted lane offsets (shorts, region-relative) ----
    const int rdA0 = mcol * 64 + ((lkb ^ (mcol & 7)) * 8);
    const int rdA1 = mcol * 64 + (((4 + lkb) ^ (mcol & 7)) * 8);
    int wr[4];
    {
        const int ub2 = u & ~1;
#pragma unroll
        for (int m = 0; m < 4; ++m) {
            const int r  = lkb * 4 + m;
            const int cc = ((q * 2 + (mcol >> 3)) ^ (r & 7));
            wr[m] = r * 64 + cc * 8 + (ub2 & 7) + (sel ? LOOFF : 0);
        }
    }

    float c0[4] = {0.f, 0.f, 0.f, 0.f};
    float c1[4] = {0.f, 0.f, 0.f, 0.f};

    __syncthreads();

    const float4* lut4 = reinterpret_cast<const float4*>(lut);

    // prefetch t=0 LUT values
    float4 lvA[4], lvB[4];
    {
        int xa0[4];
        *(int4*)xa0 = *(const int4*)&xsT[lkb * 4];
#pragma unroll
        for (int m = 0; m < 4; ++m) lvA[m] = lut4[xa0[m] * 64 + u];
    }

    for (int t2 = 0; t2 < TT / 2; ++t2) {
        const int t = t2 * 2;
        STEP(0, lvA, lvB, t);
        STEP(1, lvB, lvA, t + 1);
    }
    __syncthreads();

    // ---- FC epilogue: h1 final state lives in region (layer1, parity0) ----
#pragma unroll
    for (int s = 0; s < 2; ++s) {
        const int job = tid + s * 256;
        const int r = job >> 5;
        const int o = job & 31;
        float acc = bfc[o];
#pragma unroll
        for (int uu = 0; uu < HID; ++uu) {
            const int idx = REGB(1, 0) + r * 64 + (((uu >> 3) ^ (r & 7)) * 8) + (uu & 7);
            const float hv = bf2f(hs[idx]) + bf2f(hs[idx + LOOFF]);
            acc = fmaf(hv, Wfc[o * HID + uu], acc);
        }
        out[(r0 + r) * NOUT + o] = fmaxf(acc, 0.f);
    }
}

extern "C" void kernel_launch(void* const* d_in, const int* in_sizes, int n_in,
                              void* d_out, int out_size, void* d_ws, size_t ws_size,
                              hipStream_t stream) {
    const int*   x    = (const int*)  d_in[0];
    const float* emb  = (const float*)d_in[1];
    const float* Wih0 = (const float*)d_in[2];
    const float* Whh0 = (const float*)d_in[3];
    const float* bih0 = (const float*)d_in[4];
    const float* bhh0 = (const float*)d_in[5];
    const float* Wih1 = (const float*)d_in[6];
    const float* Whh1 = (const float*)d_in[7];
    const float* bih1 = (const float*)d_in[8];
    const float* bhh1 = (const float*)d_in[9];
    const float* Wfc  = (const float*)d_in[10];
    const float* bfc  = (const float*)d_in[11];
    float* out = (float*)d_out;
    float* lut = (float*)d_ws;   // 100*256*4 = 102,400 bytes

    hipLaunchKernelGGL(build_lut, dim3(VOCAB), dim3(G4), 0, stream,
                       emb, Wih0, bih0, bhh0, lut);
    hipLaunchKernelGGL(lstm_mfma, dim3(BATCH / BT), dim3(256), 0, stream,
                       x, Whh0, Wih1, Whh1, bih1, bhh1, Wfc, bfc, lut, out);
}

// Round 6
// 890.514 us; speedup vs baseline: 3.7995x; 3.7995x over previous
//
#include <hip/hip_runtime.h>
#include <hip/hip_bf16.h>

#define VOCAB 100
#define EMB   32
#define HID   64
#define G4    256
#define TT    200
#define BATCH 8192
#define NOUT  32
#define BT    16

// LDS h-plane geometry (units: shorts).
// HI block: [layer(2)][parity(2)][row(16)][unit(64)] = 4096 shorts, then 16-short pad,
// then LO block (same layout) at +4112 shorts => LO banks = HI banks + 8 dwords (mod 32)
// => HI-writes and LO-writes of one instruction land on complementary bank halves.
#define REGB(l, p) (((l) * 2 + (p)) * 1024)
#define LOOFF 4112
#define HSSZ  8208

typedef __attribute__((ext_vector_type(8))) short short8;
typedef __attribute__((ext_vector_type(4))) float floatx4;

__device__ __forceinline__ unsigned short f2bf(float x) {
    unsigned int b = __float_as_uint(x);
    b += 0x7FFFu + ((b >> 16) & 1u);
    return (unsigned short)(b >> 16);
}
__device__ __forceinline__ float bf2f(unsigned short u) {
    return __uint_as_float(((unsigned int)u) << 16);
}
__device__ __forceinline__ float sigf(float x) {
    return __builtin_amdgcn_rcpf(1.0f + exp2f(x * -1.4426950408889634f));
}
__device__ __forceinline__ float tanhf_(float x) {
    return 1.0f - 2.0f * __builtin_amdgcn_rcpf(1.0f + exp2f(x * 2.8853900817779268f));
}
__device__ __forceinline__ void split8(const float* __restrict__ src, short8& hi, short8& lo) {
#pragma unroll
    for (int j = 0; j < 8; ++j) {
        float w = src[j];
        unsigned short h = f2bf(w);
        unsigned short l = f2bf(w - bf2f(h));
        hi[j] = (short)h;
        lo[j] = (short)l;
    }
}

// lut[v][unit][gate] (gate-minor float4) = bih0+bhh0 + emb[v] . Wih0-row
__global__ void build_lut(const float* __restrict__ emb, const float* __restrict__ Wih0,
                          const float* __restrict__ bih0, const float* __restrict__ bhh0,
                          float* __restrict__ lut) {
    const int v = blockIdx.x;
    const int j = threadIdx.x;
    const float* e = emb + v * EMB;
    const float* w = Wih0 + j * EMB;
    float s = bih0[j] + bhh0[j];
#pragma unroll
    for (int k = 0; k < EMB; ++k) s = fmaf(e[k], w[k], s);
    lut[v * G4 + (j & 63) * 4 + (j >> 6)] = s;
}

#define MFMA(a, b, c) __builtin_amdgcn_mfma_f32_16x16x32_bf16((a), (b), (c), 0, 0, 0)

// pack pair (u_even,u_odd) hi->one dword / lo->one dword; even lane stores HI, odd stores LO.
#define PAIRPACK_STORE(hval, basep, off)                                            \
    {                                                                               \
        const float ho_ = __shfl_xor((hval), 1, 64);                                \
        const float hf_ = sel ? ho_ : (hval);                                       \
        const float hs_ = sel ? (hval) : ho_;                                       \
        unsigned int hw_;                                                           \
        asm("v_cvt_pk_bf16_f32 %0, %1, %2" : "=v"(hw_) : "v"(hf_), "v"(hs_));       \
        const float rlo_ = hf_ - __uint_as_float(hw_ << 16);                        \
        const float rhi_ = hs_ - __uint_as_float(hw_ & 0xffff0000u);                \
        unsigned int lw_;                                                           \
        asm("v_cvt_pk_bf16_f32 %0, %1, %2" : "=v"(lw_) : "v"(rlo_), "v"(rhi_));     \
        *(unsigned int*)&(basep)[(off)] = sel ? lw_ : hw_;                          \
    }

// One LSTM time step at compile-time parity P. LV = current lut float4[4], LVN = prefetch dst.
#define STEP(P, LV, LVN, tcur)                                                      \
    {                                                                               \
        const unsigned short* b0_ = &hs[REGB(0, (P))];                              \
        short8 ah0 = *(const short8*)&b0_[rdA0];                                    \
        short8 ah1 = *(const short8*)&b0_[rdA1];                                    \
        short8 al0 = *(const short8*)&b0_[rdA0 + LOOFF];                            \
        short8 al1 = *(const short8*)&b0_[rdA1 + LOOFF];                            \
        floatx4 g0[4];                                                              \
        _Pragma("unroll")                                                           \
        for (int ci = 0; ci < 4; ++ci) {                                            \
            floatx4 d = {0.f, 0.f, 0.f, 0.f};                                       \
            d = MFMA(ah0, w0h[ci][0], d); d = MFMA(ah1, w0h[ci][1], d);             \
            d = MFMA(al0, w0h[ci][0], d); d = MFMA(al1, w0h[ci][1], d);             \
            d = MFMA(ah0, w0l[ci][0], d); d = MFMA(ah1, w0l[ci][1], d);             \
            g0[ci] = d;                                                             \
        }                                                                           \
        int xa_[4];                                                                 \
        *(int4*)xa_ = *(const int4*)&xsT[((tcur) + 1) * BT + lkb * 4];              \
        _Pragma("unroll")                                                           \
        for (int m2 = 0; m2 < 4; ++m2) LVN[m2] = lut4[xa_[m2] * 64 + u];            \
        unsigned short* wb0_ = &hs[REGB(0, (P) ^ 1)];                               \
        _Pragma("unroll")                                                           \
        for (int m = 0; m < 4; ++m) {                                               \
            const float gi = g0[0][m] + LV[m].x;                                    \
            const float gf = g0[1][m] + LV[m].y;                                    \
            const float gg = g0[2][m] + LV[m].z;                                    \
            const float go = g0[3][m] + LV[m].w;                                    \
            const float c = sigf(gf) * c0[m] + sigf(gi) * tanhf_(gg);               \
            c0[m] = c;                                                              \
            const float h = sigf(go) * tanhf_(c);                                   \
            PAIRPACK_STORE(h, wb0_, wr[m]);                                         \
        }                                                                           \
        __syncthreads();                                                            \
        const unsigned short* c0_ = &hs[REGB(0, (P) ^ 1)];                          \
        const unsigned short* c1_ = &hs[REGB(1, (P))];                              \
        short8 f0 = *(const short8*)&c0_[rdA0];                                     \
        short8 f1 = *(const short8*)&c0_[rdA1];                                     \
        short8 f2 = *(const short8*)&c1_[rdA0];                                     \
        short8 f3 = *(const short8*)&c1_[rdA1];                                     \
        floatx4 g1[4];                                                              \
        _Pragma("unroll")                                                           \
        for (int ci = 0; ci < 4; ++ci) {                                            \
            floatx4 d = {b1v[ci], b1v[ci], b1v[ci], b1v[ci]};                       \
            d = MFMA(f0, w1h[ci][0], d); d = MFMA(f1, w1h[ci][1], d);               \
            d = MFMA(f2, w1h[ci][2], d); d = MFMA(f3, w1h[ci][3], d);               \
            d = MFMA(f0, w1l[ci][0], d); d = MFMA(f1, w1l[ci][1], d);               \
            d = MFMA(f2, w1l[ci][2], d); d = MFMA(f3, w1l[ci][3], d);               \
            g1[ci] = d;                                                             \
        }                                                                           \
        f0 = *(const short8*)&c0_[rdA0 + LOOFF];                                    \
        f1 = *(const short8*)&c0_[rdA1 + LOOFF];                                    \
        f2 = *(const short8*)&c1_[rdA0 + LOOFF];                                    \
        f3 = *(const short8*)&c1_[rdA1 + LOOFF];                                    \
        _Pragma("unroll")                                                           \
        for (int ci = 0; ci < 4; ++ci) {                                            \
            floatx4 d = g1[ci];                                                     \
            d = MFMA(f0, w1h[ci][0], d); d = MFMA(f1, w1h[ci][1], d);               \
            d = MFMA(f2, w1h[ci][2], d); d = MFMA(f3, w1h[ci][3], d);               \
            g1[ci] = d;                                                             \
        }                                                                           \
        unsigned short* wb1_ = &hs[REGB(1, (P) ^ 1)];                               \
        _Pragma("unroll")                                                           \
        for (int m = 0; m < 4; ++m) {                                               \
            const float c = sigf(g1[1][m]) * c1[m] + sigf(g1[0][m]) * tanhf_(g1[2][m]); \
            c1[m] = c;                                                              \
            const float h = sigf(g1[3][m]) * tanhf_(c);                             \
            PAIRPACK_STORE(h, wb1_, wr[m]);                                         \
        }                                                                           \
    }

__global__ __launch_bounds__(256, 1) void lstm_mfma(
    const int*   __restrict__ x,
    const float* __restrict__ Whh0,
    const float* __restrict__ Wih1,
    const float* __restrict__ Whh1,
    const float* __restrict__ bih1,
    const float* __restrict__ bhh1,
    const float* __restrict__ Wfc,
    const float* __restrict__ bfc,
    const float* __restrict__ lut,
    float* __restrict__ out) {

    __shared__ __align__(16) unsigned short hs[HSSZ];
    __shared__ __align__(16) int xsT[(TT + 1) * BT];

    const int tid  = threadIdx.x;
    const int lane = tid & 63;
    const int q    = tid >> 6;
    const int r0   = blockIdx.x * BT;

    // stage x transposed: xsT[t][r]
    for (int i = tid; i < BT * TT; i += 256) {
        const int r = i / TT, t = i - r * TT;
        xsT[t * BT + r] = x[r0 * TT + i];
    }
    if (tid < BT) xsT[TT * BT + tid] = 0;   // pad row (prefetch of t=200)
    for (int i = tid; i < HSSZ; i += 256) hs[i] = 0;

    const int mcol = lane & 15;
    const int lkb  = lane >> 4;
    const int u    = q * 16 + mcol;
    const int sel  = mcol & 1;

    // ---- preload weight B-frags (hi/lo split) ----
    short8 w0h[4][2], w0l[4][2], w1h[4][4], w1l[4][4];
    float  b1v[4];
#pragma unroll
    for (int ci = 0; ci < 4; ++ci) {
        const int jw = (q + ci * 4) * 16 + mcol;
#pragma unroll
        for (int kb = 0; kb < 2; ++kb)
            split8(Whh0 + jw * HID + kb * 32 + lkb * 8, w0h[ci][kb], w0l[ci][kb]);
#pragma unroll
        for (int kb = 0; kb < 4; ++kb) {
            const int k = kb * 32 + lkb * 8;
            const float* src = (k < 64) ? (Wih1 + jw * HID + k)
                                        : (Whh1 + jw * HID + (k - 64));
            split8(src, w1h[ci][kb], w1l[ci][kb]);
        }
        b1v[ci] = bih1[jw] + bhh1[jw];
    }

    // ---- hoisted lane offsets (shorts, region-relative) ----
    const int rdA0 = mcol * 64 + ((lkb ^ (mcol & 7)) * 8);
    const int rdA1 = mcol * 64 + (((4 + lkb) ^ (mcol & 7)) * 8);
    int wr[4];
    {
        const int ub2 = u & ~1;
#pragma unroll
        for (int m = 0; m < 4; ++m) {
            const int r  = lkb * 4 + m;
            const int cc = ((q * 2 + (mcol >> 3)) ^ (r & 7));
            wr[m] = r * 64 + cc * 8 + (ub2 & 7) + (sel ? LOOFF : 0);
        }
    }

    float c0[4] = {0.f, 0.f, 0.f, 0.f};
    float c1[4] = {0.f, 0.f, 0.f, 0.f};

    __syncthreads();

    const float4* lut4 = reinterpret_cast<const float4*>(lut);

    // prefetch t=0 LUT values
    float4 lvA[4], lvB[4];
    {
        int xa0[4];
        *(int4*)xa0 = *(const int4*)&xsT[lkb * 4];
#pragma unroll
        for (int m = 0; m < 4; ++m) lvA[m] = lut4[xa0[m] * 64 + u];
    }

    for (int t2 = 0; t2 < TT / 2; ++t2) {
        const int t = t2 * 2;
        STEP(0, lvA, lvB, t);
        STEP(1, lvB, lvA, t + 1);
    }
    __syncthreads();

    // ---- FC epilogue: h1 final state lives in region (layer1, parity0) ----
#pragma unroll
    for (int s = 0; s < 2; ++s) {
        const int job = tid + s * 256;
        const int r = job >> 5;
        const int o = job & 31;
        float acc = bfc[o];
#pragma unroll
        for (int uu = 0; uu < HID; ++uu) {
            const int idx = REGB(1, 0) + r * 64 + (((uu >> 3) ^ (r & 7)) * 8) + (uu & 7);
            const float hv = bf2f(hs[idx]) + bf2f(hs[idx + LOOFF]);
            acc = fmaf(hv, Wfc[o * HID + uu], acc);
        }
        out[(r0 + r) * NOUT + o] = fmaxf(acc, 0.f);
    }
}

extern "C" void kernel_launch(void* const* d_in, const int* in_sizes, int n_in,
                              void* d_out, int out_size, void* d_ws, size_t ws_size,
                              hipStream_t stream) {
    const int*   x    = (const int*)  d_in[0];
    const float* emb  = (const float*)d_in[1];
    const float* Wih0 = (const float*)d_in[2];
    const float* Whh0 = (const float*)d_in[3];
    const float* bih0 = (const float*)d_in[4];
    const float* bhh0 = (const float*)d_in[5];
    const float* Wih1 = (const float*)d_in[6];
    const float* Whh1 = (const float*)d_in[7];
    const float* bih1 = (const float*)d_in[8];
    const float* bhh1 = (const float*)d_in[9];
    const float* Wfc  = (const float*)d_in[10];
    const float* bfc  = (const float*)d_in[11];
    float* out = (float*)d_out;
    float* lut = (float*)d_ws;   // 100*256*4 = 102,400 bytes

    hipLaunchKernelGGL(build_lut, dim3(VOCAB), dim3(G4), 0, stream,
                       emb, Wih0, bih0, bhh0, lut);
    hipLaunchKernelGGL(lstm_mfma, dim3(BATCH / BT), dim3(256), 0, stream,
                       x, Whh0, Wih1, Whh1, bih1, bhh1, Wfc, bfc, lut, out);
}

// Round 8
// 633.368 us; speedup vs baseline: 5.3420x; 1.4060x over previous
//
#include <hip/hip_runtime.h>
#include <hip/hip_bf16.h>

#define VOCAB 100
#define EMB   32
#define HID   64
#define G4    256
#define TT    200
#define BATCH 8192
#define NOUT  32
#define BT    16

// LDS h-plane geometry (units: shorts).
// HI block: [layer(2)][parity(2)][row(16)][unit(64)] = 4096 shorts, then 16-short pad,
// then LO block (same layout) at +4112 shorts => LO banks = HI banks + 8 dwords (mod 32)
// => HI-writes and LO-writes of one instruction land on complementary bank halves.
#define REGB(l, p) (((l) * 2 + (p)) * 1024)
#define LOOFF 4112
#define HSSZ  8208

typedef __attribute__((ext_vector_type(8))) short short8;
typedef __attribute__((ext_vector_type(4))) float floatx4;

__device__ __forceinline__ unsigned short f2bf(float x) {
    unsigned int b = __float_as_uint(x);
    b += 0x7FFFu + ((b >> 16) & 1u);
    return (unsigned short)(b >> 16);
}
__device__ __forceinline__ float bf2f(unsigned short u) {
    return __uint_as_float(((unsigned int)u) << 16);
}
__device__ __forceinline__ float sigf(float x) {
    return __builtin_amdgcn_rcpf(1.0f + exp2f(x * -1.4426950408889634f));
}
__device__ __forceinline__ float tanhf_(float x) {
    return 1.0f - 2.0f * __builtin_amdgcn_rcpf(1.0f + exp2f(x * 2.8853900817779268f));
}
// hi-only bf16 load of 8 consecutive f32 weights (w_lo terms dropped: gates = h * bf16(w))
__device__ __forceinline__ short8 load8hi(const float* __restrict__ src) {
    short8 hi;
#pragma unroll
    for (int j = 0; j < 8; ++j) hi[j] = (short)f2bf(src[j]);
    return hi;
}

// lut[v][unit][gate] (gate-minor float4) = bih0+bhh0 + emb[v] . Wih0-row
__global__ void build_lut(const float* __restrict__ emb, const float* __restrict__ Wih0,
                          const float* __restrict__ bih0, const float* __restrict__ bhh0,
                          float* __restrict__ lut) {
    const int v = blockIdx.x;
    const int j = threadIdx.x;
    const float* e = emb + v * EMB;
    const float* w = Wih0 + j * EMB;
    float s = bih0[j] + bhh0[j];
#pragma unroll
    for (int k = 0; k < EMB; ++k) s = fmaf(e[k], w[k], s);
    lut[v * G4 + (j & 63) * 4 + (j >> 6)] = s;
}

#define MFMA(a, b, c) __builtin_amdgcn_mfma_f32_16x16x32_bf16((a), (b), (c), 0, 0, 0)

// pack pair (u_even,u_odd) hi->one dword / lo->one dword; even lane stores HI, odd stores LO.
#define PAIRPACK_STORE(hval, basep, off)                                            \
    {                                                                               \
        const float ho_ = __shfl_xor((hval), 1, 64);                                \
        const float hf_ = sel ? ho_ : (hval);                                       \
        const float hs_ = sel ? (hval) : ho_;                                       \
        unsigned int hw_;                                                           \
        asm("v_cvt_pk_bf16_f32 %0, %1, %2" : "=v"(hw_) : "v"(hf_), "v"(hs_));       \
        const float rlo_ = hf_ - __uint_as_float(hw_ << 16);                        \
        const float rhi_ = hs_ - __uint_as_float(hw_ & 0xffff0000u);                \
        unsigned int lw_;                                                           \
        asm("v_cvt_pk_bf16_f32 %0, %1, %2" : "=v"(lw_) : "v"(rlo_), "v"(rhi_));     \
        *(unsigned int*)&(basep)[(off)] = sel ? lw_ : hw_;                          \
    }

// One LSTM time step at compile-time parity P. LV = current lut float4[4], LVN = prefetch dst.
#define STEP(P, LV, LVN, tcur)                                                      \
    {                                                                               \
        const unsigned short* b0_ = &hs[REGB(0, (P))];                              \
        short8 ah0 = *(const short8*)&b0_[rdA0];                                    \
        short8 ah1 = *(const short8*)&b0_[rdA1];                                    \
        short8 al0 = *(const short8*)&b0_[rdA0 + LOOFF];                            \
        short8 al1 = *(const short8*)&b0_[rdA1 + LOOFF];                            \
        floatx4 g0[4];                                                              \
        _Pragma("unroll")                                                           \
        for (int ci = 0; ci < 4; ++ci) {                                            \
            floatx4 d = {0.f, 0.f, 0.f, 0.f};                                       \
            d = MFMA(ah0, w0h[ci][0], d); d = MFMA(ah1, w0h[ci][1], d);             \
            d = MFMA(al0, w0h[ci][0], d); d = MFMA(al1, w0h[ci][1], d);             \
            g0[ci] = d;                                                             \
        }                                                                           \
        int xa_[4];                                                                 \
        *(int4*)xa_ = *(const int4*)&xsT[((tcur) + 1) * BT + lkb * 4];              \
        _Pragma("unroll")                                                           \
        for (int m2 = 0; m2 < 4; ++m2) LVN[m2] = lut4[xa_[m2] * 64 + u];            \
        unsigned short* wb0_ = &hs[REGB(0, (P) ^ 1)];                               \
        _Pragma("unroll")                                                           \
        for (int m = 0; m < 4; ++m) {                                               \
            const float gi = g0[0][m] + LV[m].x;                                    \
            const float gf = g0[1][m] + LV[m].y;                                    \
            const float gg = g0[2][m] + LV[m].z;                                    \
            const float go = g0[3][m] + LV[m].w;                                    \
            const float c = sigf(gf) * c0[m] + sigf(gi) * tanhf_(gg);               \
            c0[m] = c;                                                              \
            const float h = sigf(go) * tanhf_(c);                                   \
            PAIRPACK_STORE(h, wb0_, wr[m]);                                         \
        }                                                                           \
        __syncthreads();                                                            \
        const unsigned short* c0_ = &hs[REGB(0, (P) ^ 1)];                          \
        const unsigned short* c1_ = &hs[REGB(1, (P))];                              \
        short8 f0 = *(const short8*)&c0_[rdA0];                                     \
        short8 f1 = *(const short8*)&c0_[rdA1];                                     \
        short8 f2 = *(const short8*)&c1_[rdA0];                                     \
        short8 f3 = *(const short8*)&c1_[rdA1];                                     \
        floatx4 g1[4];                                                              \
        _Pragma("unroll")                                                           \
        for (int ci = 0; ci < 4; ++ci) {                                            \
            floatx4 d = {b1v[ci], b1v[ci], b1v[ci], b1v[ci]};                       \
            d = MFMA(f0, w1h[ci][0], d); d = MFMA(f1, w1h[ci][1], d);               \
            d = MFMA(f2, w1h[ci][2], d); d = MFMA(f3, w1h[ci][3], d);               \
            g1[ci] = d;                                                             \
        }                                                                           \
        f0 = *(const short8*)&c0_[rdA0 + LOOFF];                                    \
        f1 = *(const short8*)&c0_[rdA1 + LOOFF];                                    \
        f2 = *(const short8*)&c1_[rdA0 + LOOFF];                                    \
        f3 = *(const short8*)&c1_[rdA1 + LOOFF];                                    \
        _Pragma("unroll")                                                           \
        for (int ci = 0; ci < 4; ++ci) {                                            \
            floatx4 d = g1[ci];                                                     \
            d = MFMA(f0, w1h[ci][0], d); d = MFMA(f1, w1h[ci][1], d);               \
            d = MFMA(f2, w1h[ci][2], d); d = MFMA(f3, w1h[ci][3], d);               \
            g1[ci] = d;                                                             \
        }                                                                           \
        unsigned short* wb1_ = &hs[REGB(1, (P) ^ 1)];                               \
        _Pragma("unroll")                                                           \
        for (int m = 0; m < 4; ++m) {                                               \
            const float c = sigf(g1[1][m]) * c1[m] + sigf(g1[0][m]) * tanhf_(g1[2][m]); \
            c1[m] = c;                                                              \
            const float h = sigf(g1[3][m]) * tanhf_(c);                             \
            PAIRPACK_STORE(h, wb1_, wr[m]);                                         \
        }                                                                           \
    }

__global__ __launch_bounds__(256, 2) void lstm_mfma(
    const int*   __restrict__ x,
    const float* __restrict__ Whh0,
    const float* __restrict__ Wih1,
    const float* __restrict__ Whh1,
    const float* __restrict__ bih1,
    const float* __restrict__ bhh1,
    const float* __restrict__ Wfc,
    const float* __restrict__ bfc,
    const float* __restrict__ lut,
    float* __restrict__ out) {

    __shared__ __align__(16) unsigned short hs[HSSZ];
    __shared__ __align__(16) int xsT[(TT + 1) * BT];

    const int tid  = threadIdx.x;
    const int lane = tid & 63;
    const int q    = tid >> 6;
    const int r0   = blockIdx.x * BT;

    // stage x transposed: xsT[t][r]
    for (int i = tid; i < BT * TT; i += 256) {
        const int r = i / TT, t = i - r * TT;
        xsT[t * BT + r] = x[r0 * TT + i];
    }
    if (tid < BT) xsT[TT * BT + tid] = 0;   // pad row (prefetch of t=200)
    for (int i = tid; i < HSSZ; i += 256) hs[i] = 0;

    const int mcol = lane & 15;
    const int lkb  = lane >> 4;
    const int u    = q * 16 + mcol;
    const int sel  = mcol & 1;

    // ---- preload weight B-frags (hi only; w_lo terms dropped) ----
    short8 w0h[4][2], w1h[4][4];
    float  b1v[4];
#pragma unroll
    for (int ci = 0; ci < 4; ++ci) {
        const int jw = (q + ci * 4) * 16 + mcol;
#pragma unroll
        for (int kb = 0; kb < 2; ++kb)
            w0h[ci][kb] = load8hi(Whh0 + jw * HID + kb * 32 + lkb * 8);
#pragma unroll
        for (int kb = 0; kb < 4; ++kb) {
            const int k = kb * 32 + lkb * 8;
            const float* src = (k < 64) ? (Wih1 + jw * HID + k)
                                        : (Whh1 + jw * HID + (k - 64));
            w1h[ci][kb] = load8hi(src);
        }
        b1v[ci] = bih1[jw] + bhh1[jw];
    }

    // ---- hoisted lane offsets (shorts, region-relative) ----
    const int rdA0 = mcol * 64 + ((lkb ^ (mcol & 7)) * 8);
    const int rdA1 = mcol * 64 + (((4 + lkb) ^ (mcol & 7)) * 8);
    int wr[4];
    {
        const int ub2 = u & ~1;
#pragma unroll
        for (int m = 0; m < 4; ++m) {
            const int r  = lkb * 4 + m;
            const int cc = ((q * 2 + (mcol >> 3)) ^ (r & 7));
            wr[m] = r * 64 + cc * 8 + (ub2 & 7) + (sel ? LOOFF : 0);
        }
    }

    float c0[4] = {0.f, 0.f, 0.f, 0.f};
    float c1[4] = {0.f, 0.f, 0.f, 0.f};

    __syncthreads();

    const float4* lut4 = reinterpret_cast<const float4*>(lut);

    // prefetch t=0 LUT values
    float4 lvA[4], lvB[4];
    {
        int xa0[4];
        *(int4*)xa0 = *(const int4*)&xsT[lkb * 4];
#pragma unroll
        for (int m = 0; m < 4; ++m) lvA[m] = lut4[xa0[m] * 64 + u];
    }

    for (int t2 = 0; t2 < TT / 2; ++t2) {
        const int t = t2 * 2;
        STEP(0, lvA, lvB, t);
        STEP(1, lvB, lvA, t + 1);
    }
    __syncthreads();

    // ---- FC epilogue: h1 final state lives in region (layer1, parity0) ----
#pragma unroll
    for (int s = 0; s < 2; ++s) {
        const int job = tid + s * 256;
        const int r = job >> 5;
        const int o = job & 31;
        float acc = bfc[o];
#pragma unroll
        for (int uu = 0; uu < HID; ++uu) {
            const int idx = REGB(1, 0) + r * 64 + (((uu >> 3) ^ (r & 7)) * 8) + (uu & 7);
            const float hv = bf2f(hs[idx]) + bf2f(hs[idx + LOOFF]);
            acc = fmaf(hv, Wfc[o * HID + uu], acc);
        }
        out[(r0 + r) * NOUT + o] = fmaxf(acc, 0.f);
    }
}

extern "C" void kernel_launch(void* const* d_in, const int* in_sizes, int n_in,
                              void* d_out, int out_size, void* d_ws, size_t ws_size,
                              hipStream_t stream) {
    const int*   x    = (const int*)  d_in[0];
    const float* emb  = (const float*)d_in[1];
    const float* Wih0 = (const float*)d_in[2];
    const float* Whh0 = (const float*)d_in[3];
    const float* bih0 = (const float*)d_in[4];
    const float* bhh0 = (const float*)d_in[5];
    const float* Wih1 = (const float*)d_in[6];
    const float* Whh1 = (const float*)d_in[7];
    const float* bih1 = (const float*)d_in[8];
    const float* bhh1 = (const float*)d_in[9];
    const float* Wfc  = (const float*)d_in[10];
    const float* bfc  = (const float*)d_in[11];
    float* out = (float*)d_out;
    float* lut = (float*)d_ws;   // 100*256*4 = 102,400 bytes

    hipLaunchKernelGGL(build_lut, dim3(VOCAB), dim3(G4), 0, stream,
                       emb, Wih0, bih0, bhh0, lut);
    hipLaunchKernelGGL(lstm_mfma, dim3(BATCH / BT), dim3(256), 0, stream,
                       x, Whh0, Wih1, Whh1, bih1, bhh1, Wfc, bfc, lut, out);
}